// Round 8
// baseline (650.840 us; speedup 1.0000x reference)
//
#include <hip/hip_runtime.h>

// ============================================================================
// MoE block (top-2 of 8 experts), T=8192 tokens, d=1024, h=2048.
// R12: keep R11's phase1 core (best measured: 163us, VGPR 56, 2 blk/CU).
// Changes:
//  1) phase2 re-tiled 256x128 -> 128x128 (4 waves, acc 4x4, 32KB LDS,
//     ~4 blk/CU): old grid 568 @ 2/CU = 1.11 rounds -> ~45% tail waste on a
//     ~160-200us kernel. New grid 1088 small blocks ~= 1.06 rounds with
//     quarter-size tail. Needs a 128-row tile prefix (tileoff128).
//  2) L2 supertiling on both GEMM grids: tiles enumerated in supertiles of
//     4 row-tiles x 8 (p1) / 4 (p2) col-tiles => working set ~2MB A + 2MB B
//     fits one XCD's 4MB L2 under the XCD-chunked remap (B stops cycling L3).
// Everything else unchanged from R11.
// ============================================================================

#define TOKS 8192
#define DIMD 1024
#define HID  2048
#define NE   8

#define OFF_COUNTS   0
#define OFF_OFFSETS  64
#define OFF_CURSORS  128
#define OFF_TILEOFF  192
#define OFF_T128     240
#define OFF_TOPKI    320
#define OFF_TOPKG    (OFF_TOPKI + TOKS*2*4)
#define OFF_BLKPS    (OFF_TOPKG + TOKS*2*4)
#define OFF_ATOK     (OFF_BLKPS + 2048*NE*4)
#define OFF_AGATE    (OFF_ATOK + TOKS*2*4)
#define OFF_PINV     (OFF_AGATE + TOKS*2*4)
#define OFF_XG       (1u << 20)
#define XG_ROWS      (TOKS*2 + 256)
#define OFF_W1B      (OFF_XG  + (size_t)XG_ROWS * DIMD * 2)
#define OFF_W2B      (OFF_W1B + (size_t)NE * HID * DIMD * 2)
#define OFF_H        (OFF_W2B + (size_t)NE * DIMD * HID * 2)
#define OFF_Y        (OFF_H   + (size_t)XG_ROWS * HID * 2)

typedef __bf16 bf16x8 __attribute__((ext_vector_type(8)));
typedef float  floatx4 __attribute__((ext_vector_type(4)));

__device__ __forceinline__ float bf2f(unsigned short u) {
    return __uint_as_float(((unsigned)u) << 16);
}
__device__ __forceinline__ unsigned short f2bf(float f) {
    unsigned u = __float_as_uint(f);
    unsigned r = (u + 0x7FFFu + ((u >> 16) & 1u)) >> 16;
    return (unsigned short)r;
}

#define GLOBAL_AS(p) ((const __attribute__((address_space(1))) unsigned int*)(p))
#define LDS_AS(p)    ((__attribute__((address_space(3))) unsigned int*)(p))

// m204 bijective XCD-chunk remap: physical bid -> logical idx.
__device__ __forceinline__ int xcd_remap(int bid, int nwg) {
    int xcd = bid & 7, pos = bid >> 3;
    int q = nwg >> 3, r = nwg & 7;
    int start = (xcd < r) ? xcd * (q + 1) : r * (q + 1) + (xcd - r) * q;
    return start + pos;
}

// ---------------------------------------------------------------------------
// Both weight tensors -> bf16 in one pass.
__global__ void convert_w_kernel(const float4* __restrict__ w1,
                                 ushort4* __restrict__ w1b, int n1,
                                 const float4* __restrict__ w2,
                                 ushort4* __restrict__ w2b, int n2) {
    int i = blockIdx.x * blockDim.x + threadIdx.x;
    int stride = gridDim.x * blockDim.x;
    int ntot = n1 + n2;
    for (; i < ntot; i += stride) {
        float4 v; ushort4 o;
        if (i < n1) v = w1[i]; else v = w2[i - n1];
        o.x = f2bf(v.x); o.y = f2bf(v.y); o.z = f2bf(v.z); o.w = f2bf(v.w);
        if (i < n1) w1b[i] = o; else w2b[i - n1] = o;
    }
}

// ---------------------------------------------------------------------------
// One wave per token: logits = x[t] . rw[e], softmax over 8, top-2, gates.
__global__ __launch_bounds__(256) void router_kernel(
    const float* __restrict__ x, const float* __restrict__ rw,
    int* __restrict__ topki, float* __restrict__ topkg,
    float* __restrict__ blkps)
{
    int wave = threadIdx.x >> 6;
    int lane = threadIdx.x & 63;
    int t = blockIdx.x * 4 + wave;
    const float* xt = x + (size_t)t * DIMD;

    float acc[NE];
#pragma unroll
    for (int e = 0; e < NE; e++) acc[e] = 0.f;
    for (int i = 0; i < DIMD / 64; i++) {
        float xv = xt[lane + 64 * i];
#pragma unroll
        for (int e = 0; e < NE; e++) acc[e] += xv * rw[e * DIMD + lane + 64 * i];
    }
#pragma unroll
    for (int off = 32; off > 0; off >>= 1) {
#pragma unroll
        for (int e = 0; e < NE; e++) acc[e] += __shfl_down(acc[e], off);
    }

    __shared__ float ps[4][NE];
    if (lane == 0) {
        float m = acc[0];
#pragma unroll
        for (int e = 1; e < NE; e++) m = fmaxf(m, acc[e]);
        float ex[NE], s = 0.f;
#pragma unroll
        for (int e = 0; e < NE; e++) { ex[e] = expf(acc[e] - m); s += ex[e]; }
        float inv = 1.f / s;
#pragma unroll
        for (int e = 0; e < NE; e++) ps[wave][e] = ex[e] * inv;

        int i0 = 0; float l0 = acc[0];
#pragma unroll
        for (int e = 1; e < NE; e++) if (acc[e] > l0) { l0 = acc[e]; i0 = e; }
        int i1 = -1; float l1 = -3.4e38f;
#pragma unroll
        for (int e = 0; e < NE; e++) if (e != i0 && acc[e] > l1) { l1 = acc[e]; i1 = e; }
        float e1 = expf(l1 - l0);
        float g0 = 1.f / (1.f + e1);
        float g1 = e1 * g0;
        topki[t * 2 + 0] = i0; topki[t * 2 + 1] = i1;
        topkg[t * 2 + 0] = g0; topkg[t * 2 + 1] = g1;
    }
    __syncthreads();
    if (threadIdx.x < NE) {
        float s = ps[0][threadIdx.x] + ps[1][threadIdx.x] + ps[2][threadIdx.x] + ps[3][threadIdx.x];
        blkps[blockIdx.x * NE + threadIdx.x] = s;
    }
}

// ---------------------------------------------------------------------------
// Single block: counts, offsets, cursors, 256- and 128-row tile prefixes,
// aux loss.
__global__ __launch_bounds__(256) void finalize_kernel(
    const int* __restrict__ topki, const float* __restrict__ blkps,
    int* __restrict__ counts, int* __restrict__ offsets, int* __restrict__ cursors,
    int* __restrict__ tileoff, int* __restrict__ tileoff128,
    float* __restrict__ aux_out)
{
    __shared__ float psum[NE];
    __shared__ int cnt[NE];
    int tid = threadIdx.x;
    if (tid < NE) { psum[tid] = 0.f; cnt[tid] = 0; }
    __syncthreads();

    float lp[NE]; int lc[NE];
#pragma unroll
    for (int e = 0; e < NE; e++) { lp[e] = 0.f; lc[e] = 0; }
    const float4* bp4 = (const float4*)blkps;
    for (int i = tid; i < 2048 * NE / 4; i += 256) {
        float4 v = bp4[i];
        int eb = (4 * i) & 7;   // 0 or 4
        lp[eb + 0] += v.x; lp[eb + 1] += v.y; lp[eb + 2] += v.z; lp[eb + 3] += v.w;
    }
    const int4* ti4 = (const int4*)topki;
    for (int i = tid; i < TOKS * 2 / 4; i += 256) {
        int4 v = ti4[i];
        lc[v.x]++; lc[v.y]++; lc[v.z]++; lc[v.w]++;
    }
#pragma unroll
    for (int e = 0; e < NE; e++) { atomicAdd(&psum[e], lp[e]); atomicAdd(&cnt[e], lc[e]); }
    __syncthreads();

    if (tid == 0) {
        int off = 0, to = 0, to1 = 0;
        for (int e = 0; e < NE; e++) {
            counts[e] = cnt[e];
            offsets[e] = off; cursors[e] = off;
            tileoff[e] = to;
            tileoff128[e] = to1;
            off += cnt[e];
            to  += (cnt[e] + 255) >> 8;    // 256-row tiles (phase1)
            to1 += (cnt[e] + 127) >> 7;    // 128-row tiles (phase2)
        }
        offsets[NE] = off; tileoff[NE] = to; tileoff128[NE] = to1;
        float aux = 0.f;
        for (int e = 0; e < NE; e++)
            aux += ((float)cnt[e] / (float)(TOKS * 2)) * (psum[e] / (float)TOKS);
        aux_out[0] = (float)NE * aux;
    }
}

// ---------------------------------------------------------------------------
// Build packed per-expert (token, gate) lists + inverse map token->position.
__global__ __launch_bounds__(64) void fill_kernel(
    const int* __restrict__ topki, const float* __restrict__ topkg,
    int* __restrict__ cursors, int* __restrict__ atok, float* __restrict__ agate,
    int* __restrict__ posinv)
{
    int lane = threadIdx.x;
    int t = blockIdx.x * 64 + lane;
    unsigned long long below = (lane == 63) ? 0x7FFFFFFFFFFFFFFFull
                                            : ((1ull << lane) - 1ull);
#pragma unroll
    for (int k = 0; k < 2; k++) {
        int e = topki[t * 2 + k];
        float g = topkg[t * 2 + k];
        for (int ee = 0; ee < NE; ee++) {
            bool pred = (e == ee);
            unsigned long long mask = __ballot(pred ? 1 : 0);
            if (mask) {
                int leader = __ffsll((unsigned long long)mask) - 1;
                int base = 0;
                if (lane == leader) base = atomicAdd(&cursors[ee], (int)__popcll(mask));
                base = __shfl(base, leader);
                if (pred) {
                    int pos = base + (int)__popcll(mask & below);
                    atok[pos] = t;
                    agate[pos] = g;
                    posinv[t * 2 + k] = pos;
                }
            }
        }
    }
}

// ---------------------------------------------------------------------------
// Gather: one block per TOKEN; read x[t] once (fp32->bf16), write BOTH
// packed rows.
__global__ __launch_bounds__(256) void gather_x_kernel(
    const float* __restrict__ x, const int* __restrict__ posinv,
    ushort* __restrict__ Xg)
{
    int t = blockIdx.x;
    int tid = threadIdx.x;
    float4 v = ((const float4*)(x + (size_t)t * DIMD))[tid];
    ushort4 o;
    o.x = f2bf(v.x); o.y = f2bf(v.y); o.z = f2bf(v.z); o.w = f2bf(v.w);
    int p0 = posinv[t * 2 + 0], p1 = posinv[t * 2 + 1];
    ((ushort4*)(Xg + (size_t)p0 * DIMD))[tid] = o;
    ((ushort4*)(Xg + (size_t)p1 * DIMD))[tid] = o;
}

// ===========================================================================
// 256x128 GEMM core (phase1), BK=32, 8 waves, 2 blocks/CU. Unchanged R11.
// LDS chunk = 16 rows x 32 k (1 KB). A chunks 0-15, B chunks 16-23.
// ===========================================================================
template<int LD, int NT>
__device__ __forceinline__ void gemm_tlp(
    const ushort* __restrict__ gApanel, const ushort* __restrict__ gBpanel,
    ushort (&lds)[2][24][512], floatx4 (&acc)[4][4],
    int lane, int wave, int wr, int wc, int l15, int quad)
{
    auto stage = [&](int bsel, int u) {
#pragma unroll
        for (int t = 0; t < 2; t++) {
            int s = wave * 2 + t;
            const ushort* a0 = gApanel + (size_t)(s * 16 + l15) * LD + u * 32 + quad * 8;
            __builtin_amdgcn_global_load_lds(GLOBAL_AS(a0),
                LDS_AS(&lds[bsel][s][0]), 16, 0, 0);
        }
        const ushort* b0 = gBpanel + (size_t)(wave * 16 + l15) * LD + u * 32 + quad * 8;
        __builtin_amdgcn_global_load_lds(GLOBAL_AS(b0),
            LDS_AS(&lds[bsel][16 + wave][0]), 16, 0, 0);
    };

#pragma unroll
    for (int i = 0; i < 4; i++)
#pragma unroll
        for (int j = 0; j < 4; j++) acc[i][j] = (floatx4){0.f, 0.f, 0.f, 0.f};

    stage(0, 0);
    __syncthreads();

    for (int u = 0; u < NT; u++) {
        if (u + 1 < NT) stage((u + 1) & 1, u + 1);   // prefetch under compute
        const bf16x8* C = (const bf16x8*)&lds[u & 1][0][0];
        bf16x8 a[4], b[4];
#pragma unroll
        for (int mi = 0; mi < 4; mi++) a[mi] = C[(wr * 4 + mi) * 64 + lane];
#pragma unroll
        for (int nj = 0; nj < 4; nj++) b[nj] = C[(16 + wc * 4 + nj) * 64 + lane];
#pragma unroll
        for (int mi = 0; mi < 4; mi++)
#pragma unroll
            for (int nj = 0; nj < 4; nj++)
                acc[mi][nj] = __builtin_amdgcn_mfma_f32_16x16x32_bf16(
                    a[mi], b[nj], acc[mi][nj], 0, 0, 0);
        __syncthreads();
    }
}

// ===========================================================================
// 128x128 GEMM core (phase2), BK=32, 4 waves, ~4 blocks/CU.
// A chunks 0-7, B chunks 8-15. 16 KiB/buf. Each wave stages 4 chunks.
// Wave (wr=wave>>1, wc=wave&1) owns 64x64 out.
// ===========================================================================
template<int LD, int NT>
__device__ __forceinline__ void gemm_tlp4(
    const ushort* __restrict__ gApanel, const ushort* __restrict__ gBpanel,
    ushort (&lds)[2][16][512], floatx4 (&acc)[4][4],
    int lane, int wave, int wr, int wc, int l15, int quad)
{
    auto stage = [&](int bsel, int u) {
#pragma unroll
        for (int t = 0; t < 4; t++) {
            int c = wave * 4 + t;
            const ushort* p = (c < 8)
                ? gApanel + (size_t)(c * 16 + l15) * LD + u * 32 + quad * 8
                : gBpanel + (size_t)((c - 8) * 16 + l15) * LD + u * 32 + quad * 8;
            __builtin_amdgcn_global_load_lds(GLOBAL_AS(p),
                LDS_AS(&lds[bsel][c][0]), 16, 0, 0);
        }
    };

#pragma unroll
    for (int i = 0; i < 4; i++)
#pragma unroll
        for (int j = 0; j < 4; j++) acc[i][j] = (floatx4){0.f, 0.f, 0.f, 0.f};

    stage(0, 0);
    __syncthreads();

    for (int u = 0; u < NT; u++) {
        if (u + 1 < NT) stage((u + 1) & 1, u + 1);
        const bf16x8* C = (const bf16x8*)&lds[u & 1][0][0];
        bf16x8 a[4], b[4];
#pragma unroll
        for (int mi = 0; mi < 4; mi++) a[mi] = C[(wr * 4 + mi) * 64 + lane];
#pragma unroll
        for (int nj = 0; nj < 4; nj++) b[nj] = C[(8 + wc * 4 + nj) * 64 + lane];
#pragma unroll
        for (int mi = 0; mi < 4; mi++)
#pragma unroll
            for (int nj = 0; nj < 4; nj++)
                acc[mi][nj] = __builtin_amdgcn_mfma_f32_16x16x32_bf16(
                    a[mi], b[nj], acc[mi][nj], 0, 0, 0);
        __syncthreads();
    }
}

// ---------------------------------------------------------------------------
// Phase 1: H = gelu(Xg @ w1b[e]^T + b1[e]). 256x128 tiles, supertiled grid:
// supertile = 4 row-tiles x 8 col-tiles (A 2MB + B 2MB = one XCD L2).
__global__ __launch_bounds__(512, 4) void phase1_kernel(
    const ushort* __restrict__ Xg, const ushort* __restrict__ w1b,
    const float* __restrict__ b1,
    const int* __restrict__ counts, const int* __restrict__ offsets,
    const int* __restrict__ tileoff, unsigned short* __restrict__ Hbuf)
{
    int T1 = tileoff[NE];
    int T1p = (T1 + 3) & ~3;
    int g = xcd_remap((int)blockIdx.x, (int)gridDim.x);
    if (g >= T1p * 16) return;
    int s = g >> 5, u = g & 31;           // supertile id / pos (4x8)
    int srow = s >> 1, scol = s & 1;      // 2 supercols of 8 ct
    int rowt = srow * 4 + (u >> 3);
    int ct   = scol * 8 + (u & 7);
    if (rowt >= T1) return;
    int e = 0;
    while (rowt >= tileoff[e + 1]) e++;
    int row0 = (rowt - tileoff[e]) * 256;
    int cnt = counts[e];
    int base = offsets[e];
    int colbase = ct * 128;

    __shared__ ushort lds[2][24][512];   // 48 KiB

    int tid = threadIdx.x;
    int lane = tid & 63;
    int wave = tid >> 6;
    int wr = wave >> 1, wc = wave & 1;
    int l15 = lane & 15, quad = lane >> 4;

    const ushort* gApanel = Xg + (size_t)(base + row0) * DIMD;
    const ushort* gBpanel = w1b + (size_t)e * HID * DIMD + (size_t)colbase * DIMD;

    floatx4 acc[4][4];
    gemm_tlp<DIMD, DIMD / 32>(gApanel, gBpanel, lds, acc, lane, wave, wr, wc, l15, quad);

    // epilogue: bias + exact GELU, bf16 store. C/D: col=lane&15, row=quad*4+reg
    float b1v[4];
#pragma unroll
    for (int j = 0; j < 4; j++)
        b1v[j] = b1[e * HID + colbase + 64 * wc + 16 * j + l15];
#pragma unroll
    for (int i = 0; i < 4; i++) {
#pragma unroll
        for (int rr = 0; rr < 4; rr++) {
            int pr = row0 + 64 * wr + 16 * i + quad * 4 + rr;
            if (pr < cnt) {
                size_t hrow = (size_t)(base + pr) * HID;
#pragma unroll
                for (int j = 0; j < 4; j++) {
                    int col = colbase + 64 * wc + 16 * j + l15;
                    float v = acc[i][j][rr] + b1v[j];
                    v = 0.5f * v * (1.f + erff(v * 0.70710678118654752f));
                    Hbuf[hrow + col] = f2bf(v);
                }
            }
        }
    }
}

// ---------------------------------------------------------------------------
// Phase 2: Y = H @ w2b[e]^T. 128x128 tiles (tail-smooth grid), supertile =
// 4 row-tiles x 4 col-tiles (A 2MB + B 2MB L2-resident).
__global__ __launch_bounds__(256, 4) void phase2_kernel(
    const ushort* __restrict__ Hbuf, const ushort* __restrict__ w2b,
    const int* __restrict__ counts, const int* __restrict__ offsets,
    const int* __restrict__ t128, ushort* __restrict__ Y)
{
    int T2 = t128[NE];
    int T2p = (T2 + 3) & ~3;
    int g = xcd_remap((int)blockIdx.x, (int)gridDim.x);
    if (g >= T2p * 8) return;
    int s = g >> 4, u = g & 15;           // supertile id / pos (4x4)
    int srow = s >> 1, scol = s & 1;      // 2 supercols of 4 ct
    int rowt = srow * 4 + (u >> 2);
    int ct   = scol * 4 + (u & 3);
    if (rowt >= T2) return;
    int e = 0;
    while (rowt >= t128[e + 1]) e++;
    int row0 = (rowt - t128[e]) * 128;
    int cnt = counts[e];
    int base = offsets[e];
    int colbase = ct * 128;

    __shared__ ushort lds[2][16][512];   // 32 KiB

    int tid = threadIdx.x;
    int lane = tid & 63;
    int wave = tid >> 6;
    int wr = wave >> 1, wc = wave & 1;
    int l15 = lane & 15, quad = lane >> 4;

    const ushort* gApanel = Hbuf + (size_t)(base + row0) * HID;
    const ushort* gBpanel = w2b + (size_t)e * DIMD * HID + (size_t)colbase * HID;

    floatx4 acc[4][4];
    gemm_tlp4<HID, HID / 32>(gApanel, gBpanel, lds, acc, lane, wave, wr, wc, l15, quad);

    // epilogue: plain bf16 store (bias+gate applied in combine)
#pragma unroll
    for (int i = 0; i < 4; i++) {
#pragma unroll
        for (int rr = 0; rr < 4; rr++) {
            int pr = row0 + 64 * wr + 16 * i + quad * 4 + rr;
            if (pr < cnt) {
                size_t yrow = (size_t)(base + pr) * DIMD;
#pragma unroll
                for (int j = 0; j < 4; j++) {
                    int col = colbase + 64 * wc + 16 * j + l15;
                    Y[yrow + col] = f2bf(acc[i][j][rr]);
                }
            }
        }
    }
}

// ---------------------------------------------------------------------------
// Combine: out[t,:] = g0*(Y[p0,:]+b2[e0,:]) + g1*(Y[p1,:]+b2[e1,:]).
__global__ __launch_bounds__(256) void combine_kernel(
    const ushort* __restrict__ Y, const float* __restrict__ b2,
    const int* __restrict__ topki, const float* __restrict__ topkg,
    const int* __restrict__ posinv, float* __restrict__ out)
{
    int wave = threadIdx.x >> 6;
    int lane = threadIdx.x & 63;
    int t = blockIdx.x * 4 + wave;
    int e0 = topki[t * 2 + 0], e1 = topki[t * 2 + 1];
    float g0 = topkg[t * 2 + 0], g1 = topkg[t * 2 + 1];
    int p0 = posinv[t * 2 + 0], p1 = posinv[t * 2 + 1];

    const ushort4* y0 = (const ushort4*)(Y + (size_t)p0 * DIMD);
    const ushort4* y1 = (const ushort4*)(Y + (size_t)p1 * DIMD);
    const float4* b20 = (const float4*)(b2 + (size_t)e0 * DIMD);
    const float4* b21 = (const float4*)(b2 + (size_t)e1 * DIMD);
    float4* o4 = (float4*)(out + (size_t)t * DIMD);

#pragma unroll
    for (int c = 0; c < DIMD / 4 / 64; c++) {   // 4 iterations
        int i = lane + 64 * c;
        ushort4 a = y0[i], b = y1[i];
        float4 ba = b20[i], bb = b21[i];
        float4 r;
        r.x = g0 * (bf2f(a.x) + ba.x) + g1 * (bf2f(b.x) + bb.x);
        r.y = g0 * (bf2f(a.y) + ba.y) + g1 * (bf2f(b.y) + bb.y);
        r.z = g0 * (bf2f(a.z) + ba.z) + g1 * (bf2f(b.z) + bb.z);
        r.w = g0 * (bf2f(a.w) + ba.w) + g1 * (bf2f(b.w) + bb.w);
        o4[i] = r;
    }
}

// ---------------------------------------------------------------------------
extern "C" void kernel_launch(void* const* d_in, const int* in_sizes, int n_in,
                              void* d_out, int out_size, void* d_ws, size_t ws_size,
                              hipStream_t stream) {
    const float* x  = (const float*)d_in[0];
    const float* rw = (const float*)d_in[1];
    const float* w1 = (const float*)d_in[2];
    const float* b1 = (const float*)d_in[3];
    const float* w2 = (const float*)d_in[4];
    const float* b2 = (const float*)d_in[5];
    float* out = (float*)d_out;

    char* ws = (char*)d_ws;
    int*   counts  = (int*)(ws + OFF_COUNTS);
    int*   offsets = (int*)(ws + OFF_OFFSETS);
    int*   cursors = (int*)(ws + OFF_CURSORS);
    int*   tileoff = (int*)(ws + OFF_TILEOFF);
    int*   t128    = (int*)(ws + OFF_T128);
    int*   topki   = (int*)(ws + OFF_TOPKI);
    float* topkg   = (float*)(ws + OFF_TOPKG);
    float* blkps   = (float*)(ws + OFF_BLKPS);
    int*   atok    = (int*)(ws + OFF_ATOK);
    float* agate   = (float*)(ws + OFF_AGATE);
    int*   posinv  = (int*)(ws + OFF_PINV);
    ushort* Xg     = (ushort*)(ws + OFF_XG);
    ushort* w1b    = (ushort*)(ws + OFF_W1B);
    ushort* w2b    = (ushort*)(ws + OFF_W2B);
    ushort* Hbuf   = (ushort*)(ws + OFF_H);
    ushort* Y      = (ushort*)(ws + OFF_Y);

    // weight conversions (independent of routing), one pass
    convert_w_kernel<<<8192, 256, 0, stream>>>(
        (const float4*)w1, (ushort4*)w1b, NE * HID * DIMD / 4,
        (const float4*)w2, (ushort4*)w2b, NE * DIMD * HID / 4);

    router_kernel<<<TOKS / 4, 256, 0, stream>>>(x, rw, topki, topkg, blkps);
    finalize_kernel<<<1, 256, 0, stream>>>(topki, blkps, counts, offsets, cursors,
                                           tileoff, t128,
                                           out + (size_t)TOKS * DIMD);
    fill_kernel<<<TOKS / 64, 64, 0, stream>>>(topki, topkg, cursors, atok, agate,
                                              posinv);
    gather_x_kernel<<<TOKS, 256, 0, stream>>>(x, posinv, Xg);

    // phase1: worst-case 256-row tiles = 71 -> padded 72 -> 72/4 * 2 * 32 = 1152
    phase1_kernel<<<1152, 512, 0, stream>>>(
        Xg, w1b, b1, counts, offsets, tileoff, Hbuf);
    // phase2: worst-case 128-row tiles = 135 -> padded 136 -> 136/4 * 2 * 16 = 1088
    phase2_kernel<<<1088, 256, 0, stream>>>(
        Hbuf, w2b, counts, offsets, t128, Y);
    combine_kernel<<<TOKS / 4, 256, 0, stream>>>(Y, b2, topki, topkg, posinv, out);
}